// Round 4
// baseline (72.528 us; speedup 1.0000x reference)
//
#include <hip/hip_runtime.h>
#include <hip/hip_bf16.h>

// CosSim_Loss: pred [32, 8, 512, 512] f32 -> scalar mean of per-batch 8x8
// cosine-similarity Gram matrices (diag forced to 1).
//
// Round-4: (a) __launch_bounds__(256,4) to cap partial at 128 VGPR ->
// 4 blocks/CU (16 waves/CU) for 2x latency tolerance on the L3-hit portion;
// (b) finalize reads its 32-float group as 8 concurrent float4 (was scalar).
// Register budget: cur(32)+nxt(36... acc 36)+addr ~ 115 -> should fit 128.
//
// ws layout: float pw[NB][NACC][GX] = 32*36*32*4 = 147456 B.

#define NB 32      // batches
#define NM 8       // maps per batch
#define L4 65536   // (512*512)/4 float4 per row
#define NACC 36    // 8 norms + 28 pairs
#define GX 32      // blocks per batch
#define ITERS 8    // L4 / (GX*256)

template <bool DIRECT>
__global__ __launch_bounds__(256, 4) void cossim_partial(
    const float4* __restrict__ x, float* __restrict__ ws) {
    const int b = blockIdx.y;
    const float4* base = x + (size_t)b * NM * L4;

    float acc[NACC];
    #pragma unroll
    for (int k = 0; k < NACC; ++k) acc[k] = 0.0f;

    const int nthreads = GX * 256;   // 8192 threads per batch
    int l = blockIdx.x * blockDim.x + threadIdx.x;

    float4 cur[NM], nxt[NM];
    #pragma unroll
    for (int i = 0; i < NM; ++i) cur[i] = base[(size_t)i * L4 + l];

    #pragma unroll
    for (int it = 0; it < ITERS; ++it) {
        const int ln = l + nthreads;
        if (it < ITERS - 1) {
            #pragma unroll
            for (int i = 0; i < NM; ++i) nxt[i] = base[(size_t)i * L4 + ln];
        }

        #pragma unroll
        for (int i = 0; i < NM; ++i) {
            acc[i] += cur[i].x * cur[i].x + cur[i].y * cur[i].y
                    + cur[i].z * cur[i].z + cur[i].w * cur[i].w;
        }
        int k = NM;
        #pragma unroll
        for (int i = 0; i < NM; ++i) {
            #pragma unroll
            for (int j = i + 1; j < NM; ++j) {
                acc[k] += cur[i].x * cur[j].x + cur[i].y * cur[j].y
                        + cur[i].z * cur[j].z + cur[i].w * cur[j].w;
                ++k;
            }
        }

        if (it < ITERS - 1) {
            #pragma unroll
            for (int i = 0; i < NM; ++i) cur[i] = nxt[i];
        }
        l = ln;
    }

    // wave64 shuffle reduction per accumulator
    #pragma unroll
    for (int k = 0; k < NACC; ++k) {
        float s = acc[k];
        #pragma unroll
        for (int off = 32; off > 0; off >>= 1) s += __shfl_down(s, off, 64);
        acc[k] = s;   // valid in lane 0 of each wave
    }

    // block-level reduction in LDS: 4 waves -> 36 values
    __shared__ float red[4][NACC];
    const int wave = threadIdx.x >> 6;
    if ((threadIdx.x & 63) == 0) {
        #pragma unroll
        for (int k = 0; k < NACC; ++k) red[wave][k] = acc[k];
    }
    __syncthreads();
    if (threadIdx.x < NACC) {
        float s = red[0][threadIdx.x] + red[1][threadIdx.x]
                + red[2][threadIdx.x] + red[3][threadIdx.x];
        if (DIRECT) {
            ws[((size_t)b * NACC + threadIdx.x) * GX + blockIdx.x] = s;
        } else {
            atomicAdd(&ws[b * NACC + threadIdx.x], s);
        }
    }
}

__device__ __forceinline__ float batch_score(const float* w) {
    // w[0..7] = sumsq, w[8..35] = cross dots (i<j)
    float n[NM];
    #pragma unroll
    for (int i = 0; i < NM; ++i) n[i] = fmaxf(sqrtf(w[i]), 1e-8f);
    float s = 0.0f;
    int k = NM;
    #pragma unroll
    for (int i = 0; i < NM; ++i) {
        #pragma unroll
        for (int j = i + 1; j < NM; ++j) {
            s += w[k] / (n[i] * n[j]);
            ++k;
        }
    }
    return 2.0f * s + (float)NM;
}

__global__ __launch_bounds__(1024) void cossim_finalize_direct(
    const float* __restrict__ pw, float* __restrict__ out) {
    __shared__ float red[NB][NACC];
    const int tid = threadIdx.x;

    for (int p = tid; p < NB * NACC; p += 1024) {
        const float4* src = (const float4*)(pw + (size_t)p * GX);
        float4 s0 = src[0], s1 = src[1], s2 = src[2], s3 = src[3];
        float4 s4 = src[4], s5 = src[5], s6 = src[6], s7 = src[7];
        float s = (s0.x + s0.y + s0.z + s0.w) + (s1.x + s1.y + s1.z + s1.w)
                + (s2.x + s2.y + s2.z + s2.w) + (s3.x + s3.y + s3.z + s3.w)
                + (s4.x + s4.y + s4.z + s4.w) + (s5.x + s5.y + s5.z + s5.w)
                + (s6.x + s6.y + s6.z + s6.w) + (s7.x + s7.y + s7.z + s7.w);
        red[p / NACC][p % NACC] = s;
    }
    __syncthreads();

    if (tid < 64) {
        float bs = (tid < NB) ? batch_score(red[tid]) : 0.0f;
        #pragma unroll
        for (int off = 32; off > 0; off >>= 1) bs += __shfl_down(bs, off, 64);
        if (tid == 0) out[0] = bs / (float)(NB * NM * NM);
    }
}

__global__ __launch_bounds__(64) void cossim_finalize_atomic(
    const float* __restrict__ ws, float* __restrict__ out) {
    const int b = threadIdx.x;
    float bs = (b < NB) ? batch_score(ws + b * NACC) : 0.0f;
    #pragma unroll
    for (int off = 32; off > 0; off >>= 1) bs += __shfl_down(bs, off, 64);
    if (threadIdx.x == 0) out[0] = bs / (float)(NB * NM * NM);
}

extern "C" void kernel_launch(void* const* d_in, const int* in_sizes, int n_in,
                              void* d_out, int out_size, void* d_ws, size_t ws_size,
                              hipStream_t stream) {
    const float4* x = (const float4*)d_in[0];
    float* out = (float*)d_out;
    float* ws = (float*)d_ws;

    dim3 grid(GX, NB);   // 32 chunks per batch x 32 batches = 1024 blocks

    if (ws_size >= (size_t)NB * NACC * GX * sizeof(float)) {
        cossim_partial<true><<<grid, 256, 0, stream>>>(x, ws);
        cossim_finalize_direct<<<1, 1024, 0, stream>>>(ws, out);
    } else {
        hipMemsetAsync(ws, 0, NB * NACC * sizeof(float), stream);
        cossim_partial<false><<<grid, 256, 0, stream>>>(x, ws);
        cossim_finalize_atomic<<<1, 64, 0, stream>>>(ws, out);
    }
}

// Round 5
// 53.497 us; speedup vs baseline: 1.3557x; 1.3557x over previous
//
#include <hip/hip_runtime.h>
#include <hip/hip_bf16.h>

// CosSim_Loss: pred [32, 8, 512, 512] f32 -> scalar mean of per-batch 8x8
// cosine-similarity Gram matrices (diag forced to 1).
//
// Round-5: R4's (256,4) regression proved the reg-staged loop needs >128 VGPR.
// Switch staging to global_load_lds (no VGPR round-trip): each thread
// prefetches its own 8x16B slots into LDS (lane-linear layout => LDS is a
// thread-private prefetch buffer => NO barriers; ordering via per-wave counted
// s_waitcnt vmcnt(8)). 2x32KB LDS double buffer, 2 blocks/CU, 32KB in flight
// per block. VGPR ~85 (v[8] + acc[36] + addr).
//
// ws layout: float pw[NB][NACC][GX] = 32*36*16*4 = 73728 B.

#define NB 32      // batches
#define NM 8       // maps per batch
#define L4 65536   // (512*512)/4 float4 per row
#define NACC 36    // 8 norms + 28 pairs
#define GX 16      // blocks per batch -> 512 blocks, all co-resident at 2/CU
#define CH 256     // float4 per row per chunk (4 KB/row, 32 KB all rows)
#define ITERS 16   // (L4/GX)/CH

template <bool DIRECT>
__global__ __launch_bounds__(256, 2) void cossim_partial(
    const float4* __restrict__ x, float* __restrict__ ws) {
    __shared__ float4 buf[2][NM][CH];   // 64 KB
    const int b = blockIdx.y;
    const int tid = threadIdx.x;
    // this thread's slot in chunk 0 of row 0 for this block
    const float4* g = x + (size_t)b * NM * L4 + (size_t)blockIdx.x * (L4 / GX) + tid;

    // prologue: stage chunk 0 -> buf[0]
    #pragma unroll
    for (int i = 0; i < NM; ++i) {
        __builtin_amdgcn_global_load_lds(
            (const __attribute__((address_space(1))) void*)(g + (size_t)i * L4),
            (__attribute__((address_space(3))) void*)(&buf[0][i][tid]),
            16, 0, 0);
    }

    float acc[NACC];
    #pragma unroll
    for (int k = 0; k < NACC; ++k) acc[k] = 0.0f;

    for (int it = 0; it < ITERS; ++it) {
        if (it + 1 < ITERS) {
            const float4* gn = g + (size_t)(it + 1) * CH;
            #pragma unroll
            for (int i = 0; i < NM; ++i) {
                __builtin_amdgcn_global_load_lds(
                    (const __attribute__((address_space(1))) void*)(gn + (size_t)i * L4),
                    (__attribute__((address_space(3))) void*)(&buf[(it + 1) & 1][i][tid]),
                    16, 0, 0);
            }
            // our own chunk-it loads (issued last iter) are the oldest 8 of 16
            asm volatile("s_waitcnt vmcnt(8)" ::: "memory");
        } else {
            asm volatile("s_waitcnt vmcnt(0)" ::: "memory");
        }

        float4 v[NM];
        #pragma unroll
        for (int i = 0; i < NM; ++i) v[i] = buf[it & 1][i][tid];

        #pragma unroll
        for (int i = 0; i < NM; ++i) {
            acc[i] += v[i].x * v[i].x + v[i].y * v[i].y
                    + v[i].z * v[i].z + v[i].w * v[i].w;
        }
        int k = NM;
        #pragma unroll
        for (int i = 0; i < NM; ++i) {
            #pragma unroll
            for (int j = i + 1; j < NM; ++j) {
                acc[k] += v[i].x * v[j].x + v[i].y * v[j].y
                        + v[i].z * v[j].z + v[i].w * v[j].w;
                ++k;
            }
        }
    }

    // wave64 shuffle reduction per accumulator
    #pragma unroll
    for (int k = 0; k < NACC; ++k) {
        float s = acc[k];
        #pragma unroll
        for (int off = 32; off > 0; off >>= 1) s += __shfl_down(s, off, 64);
        acc[k] = s;   // valid in lane 0 of each wave
    }

    // block-level reduction in LDS: 4 waves -> 36 values
    __shared__ float red[4][NACC];
    const int wave = threadIdx.x >> 6;
    if ((threadIdx.x & 63) == 0) {
        #pragma unroll
        for (int k = 0; k < NACC; ++k) red[wave][k] = acc[k];
    }
    __syncthreads();
    if (threadIdx.x < NACC) {
        float s = red[0][threadIdx.x] + red[1][threadIdx.x]
                + red[2][threadIdx.x] + red[3][threadIdx.x];
        if (DIRECT) {
            ws[((size_t)b * NACC + threadIdx.x) * GX + blockIdx.x] = s;
        } else {
            atomicAdd(&ws[b * NACC + threadIdx.x], s);
        }
    }
}

__device__ __forceinline__ float batch_score(const float* w) {
    // w[0..7] = sumsq, w[8..35] = cross dots (i<j)
    float n[NM];
    #pragma unroll
    for (int i = 0; i < NM; ++i) n[i] = fmaxf(sqrtf(w[i]), 1e-8f);
    float s = 0.0f;
    int k = NM;
    #pragma unroll
    for (int i = 0; i < NM; ++i) {
        #pragma unroll
        for (int j = i + 1; j < NM; ++j) {
            s += w[k] / (n[i] * n[j]);
            ++k;
        }
    }
    return 2.0f * s + (float)NM;
}

__global__ __launch_bounds__(1024) void cossim_finalize_direct(
    const float* __restrict__ pw, float* __restrict__ out) {
    __shared__ float red[NB][NACC];
    const int tid = threadIdx.x;

    for (int p = tid; p < NB * NACC; p += 1024) {
        const float4* src = (const float4*)(pw + (size_t)p * GX);
        float4 s0 = src[0], s1 = src[1], s2 = src[2], s3 = src[3];
        float s = (s0.x + s0.y + s0.z + s0.w) + (s1.x + s1.y + s1.z + s1.w)
                + (s2.x + s2.y + s2.z + s2.w) + (s3.x + s3.y + s3.z + s3.w);
        red[p / NACC][p % NACC] = s;
    }
    __syncthreads();

    if (tid < 64) {
        float bs = (tid < NB) ? batch_score(red[tid]) : 0.0f;
        #pragma unroll
        for (int off = 32; off > 0; off >>= 1) bs += __shfl_down(bs, off, 64);
        if (tid == 0) out[0] = bs / (float)(NB * NM * NM);
    }
}

__global__ __launch_bounds__(64) void cossim_finalize_atomic(
    const float* __restrict__ ws, float* __restrict__ out) {
    const int b = threadIdx.x;
    float bs = (b < NB) ? batch_score(ws + b * NACC) : 0.0f;
    #pragma unroll
    for (int off = 32; off > 0; off >>= 1) bs += __shfl_down(bs, off, 64);
    if (threadIdx.x == 0) out[0] = bs / (float)(NB * NM * NM);
}

extern "C" void kernel_launch(void* const* d_in, const int* in_sizes, int n_in,
                              void* d_out, int out_size, void* d_ws, size_t ws_size,
                              hipStream_t stream) {
    const float4* x = (const float4*)d_in[0];
    float* out = (float*)d_out;
    float* ws = (float*)d_ws;

    dim3 grid(GX, NB);   // 16 chunks per batch x 32 batches = 512 blocks

    if (ws_size >= (size_t)NB * NACC * GX * sizeof(float)) {
        cossim_partial<true><<<grid, 256, 0, stream>>>(x, ws);
        cossim_finalize_direct<<<1, 1024, 0, stream>>>(ws, out);
    } else {
        hipMemsetAsync(ws, 0, NB * NACC * sizeof(float), stream);
        cossim_partial<false><<<grid, 256, 0, stream>>>(x, ws);
        cossim_finalize_atomic<<<1, 64, 0, stream>>>(ws, out);
    }
}

// Round 6
// 53.436 us; speedup vs baseline: 1.3573x; 1.0011x over previous
//
#include <hip/hip_runtime.h>
#include <hip/hip_bf16.h>

// CosSim_Loss: pred [32, 8, 512, 512] f32 -> scalar mean of per-batch 8x8
// cosine-similarity Gram matrices (diag forced to 1).
//
// Round-6: R3 (reg-staged) and R5 (global_load_lds) both land ~54 us ->
// memory-path service rate, not latency, is the limit. Attack DRAM stream
// locality: 512-thread blocks, CH=512 float4 -> each of the 8 row-streams
// advances in 8KB contiguous bursts (was 4KB), halving stream switches.
// 2x64KB LDS double buffer, 1 block/CU (8 waves, 2/SIMD - same occupancy as
// R5), 256 blocks = exactly one per CU, no tail. Lane-linear LDS slots =>
// no barriers; per-wave counted s_waitcnt vmcnt(8) orders chunk n vs n+1.
//
// ws layout: float pw[NB][NACC][GX] = 32*36*8*4 = 36864 B.

#define NB 32      // batches
#define NM 8       // maps per batch
#define L4 65536   // (512*512)/4 float4 per row
#define NACC 36    // 8 norms + 28 pairs
#define GX 8       // blocks per batch -> 256 blocks, 1/CU
#define TPB 512    // threads per block (8 waves)
#define CH 512     // float4 per row per chunk (8 KB/row, 64 KB all rows)
#define ITERS 16   // (L4/GX)/CH = 8192/512

template <bool DIRECT>
__global__ __launch_bounds__(TPB, 1) void cossim_partial(
    const float4* __restrict__ x, float* __restrict__ ws) {
    __shared__ float4 buf[2][NM][CH];   // 128 KB
    const int b = blockIdx.y;
    const int tid = threadIdx.x;
    // this thread's slot in chunk 0 of row 0 for this block
    const float4* g = x + (size_t)b * NM * L4 + (size_t)blockIdx.x * (L4 / GX) + tid;

    // prologue: stage chunk 0 -> buf[0]
    #pragma unroll
    for (int i = 0; i < NM; ++i) {
        __builtin_amdgcn_global_load_lds(
            (const __attribute__((address_space(1))) void*)(g + (size_t)i * L4),
            (__attribute__((address_space(3))) void*)(&buf[0][i][tid]),
            16, 0, 0);
    }

    float acc[NACC];
    #pragma unroll
    for (int k = 0; k < NACC; ++k) acc[k] = 0.0f;

    for (int it = 0; it < ITERS; ++it) {
        if (it + 1 < ITERS) {
            const float4* gn = g + (size_t)(it + 1) * CH;
            #pragma unroll
            for (int i = 0; i < NM; ++i) {
                __builtin_amdgcn_global_load_lds(
                    (const __attribute__((address_space(1))) void*)(gn + (size_t)i * L4),
                    (__attribute__((address_space(3))) void*)(&buf[(it + 1) & 1][i][tid]),
                    16, 0, 0);
            }
            // our own chunk-it loads (issued last iter) are the oldest 8 of 16
            asm volatile("s_waitcnt vmcnt(8)" ::: "memory");
        } else {
            asm volatile("s_waitcnt vmcnt(0)" ::: "memory");
        }

        float4 v[NM];
        #pragma unroll
        for (int i = 0; i < NM; ++i) v[i] = buf[it & 1][i][tid];

        #pragma unroll
        for (int i = 0; i < NM; ++i) {
            acc[i] += v[i].x * v[i].x + v[i].y * v[i].y
                    + v[i].z * v[i].z + v[i].w * v[i].w;
        }
        int k = NM;
        #pragma unroll
        for (int i = 0; i < NM; ++i) {
            #pragma unroll
            for (int j = i + 1; j < NM; ++j) {
                acc[k] += v[i].x * v[j].x + v[i].y * v[j].y
                        + v[i].z * v[j].z + v[i].w * v[j].w;
                ++k;
            }
        }
    }

    // wave64 shuffle reduction per accumulator
    #pragma unroll
    for (int k = 0; k < NACC; ++k) {
        float s = acc[k];
        #pragma unroll
        for (int off = 32; off > 0; off >>= 1) s += __shfl_down(s, off, 64);
        acc[k] = s;   // valid in lane 0 of each wave
    }

    // block-level reduction in LDS: 8 waves -> 36 values
    __shared__ float red[TPB / 64][NACC];
    const int wave = threadIdx.x >> 6;
    if ((threadIdx.x & 63) == 0) {
        #pragma unroll
        for (int k = 0; k < NACC; ++k) red[wave][k] = acc[k];
    }
    __syncthreads();
    if (threadIdx.x < NACC) {
        float s = 0.0f;
        #pragma unroll
        for (int w = 0; w < TPB / 64; ++w) s += red[w][threadIdx.x];
        if (DIRECT) {
            ws[((size_t)b * NACC + threadIdx.x) * GX + blockIdx.x] = s;
        } else {
            atomicAdd(&ws[b * NACC + threadIdx.x], s);
        }
    }
}

__device__ __forceinline__ float batch_score(const float* w) {
    // w[0..7] = sumsq, w[8..35] = cross dots (i<j)
    float n[NM];
    #pragma unroll
    for (int i = 0; i < NM; ++i) n[i] = fmaxf(sqrtf(w[i]), 1e-8f);
    float s = 0.0f;
    int k = NM;
    #pragma unroll
    for (int i = 0; i < NM; ++i) {
        #pragma unroll
        for (int j = i + 1; j < NM; ++j) {
            s += w[k] / (n[i] * n[j]);
            ++k;
        }
    }
    return 2.0f * s + (float)NM;
}

__global__ __launch_bounds__(1024) void cossim_finalize_direct(
    const float* __restrict__ pw, float* __restrict__ out) {
    __shared__ float red[NB][NACC];
    const int tid = threadIdx.x;

    for (int p = tid; p < NB * NACC; p += 1024) {
        const float4* src = (const float4*)(pw + (size_t)p * GX);
        float4 s0 = src[0], s1 = src[1];
        float s = (s0.x + s0.y + s0.z + s0.w) + (s1.x + s1.y + s1.z + s1.w);
        red[p / NACC][p % NACC] = s;
    }
    __syncthreads();

    if (tid < 64) {
        float bs = (tid < NB) ? batch_score(red[tid]) : 0.0f;
        #pragma unroll
        for (int off = 32; off > 0; off >>= 1) bs += __shfl_down(bs, off, 64);
        if (tid == 0) out[0] = bs / (float)(NB * NM * NM);
    }
}

__global__ __launch_bounds__(64) void cossim_finalize_atomic(
    const float* __restrict__ ws, float* __restrict__ out) {
    const int b = threadIdx.x;
    float bs = (b < NB) ? batch_score(ws + b * NACC) : 0.0f;
    #pragma unroll
    for (int off = 32; off > 0; off >>= 1) bs += __shfl_down(bs, off, 64);
    if (threadIdx.x == 0) out[0] = bs / (float)(NB * NM * NM);
}

extern "C" void kernel_launch(void* const* d_in, const int* in_sizes, int n_in,
                              void* d_out, int out_size, void* d_ws, size_t ws_size,
                              hipStream_t stream) {
    const float4* x = (const float4*)d_in[0];
    float* out = (float*)d_out;
    float* ws = (float*)d_ws;

    dim3 grid(GX, NB);   // 8 chunks per batch x 32 batches = 256 blocks

    if (ws_size >= (size_t)NB * NACC * GX * sizeof(float)) {
        cossim_partial<true><<<grid, TPB, 0, stream>>>(x, ws);
        cossim_finalize_direct<<<1, 1024, 0, stream>>>(ws, out);
    } else {
        hipMemsetAsync(ws, 0, NB * NACC * sizeof(float), stream);
        cossim_partial<false><<<grid, TPB, 0, stream>>>(x, ws);
        cossim_finalize_atomic<<<1, 64, 0, stream>>>(ws, out);
    }
}